// Round 8
// baseline (489.812 us; speedup 1.0000x reference)
//
#include <hip/hip_runtime.h>

#define SEQ 4096
#define DMODEL 1024
#define DSTATE 64
#define DINNER 2048
#define MROWS 8192            // BATCH*SEQ
#define NCHUNK 64             // scan chunks
#define LCHUNK 64             // steps per chunk

typedef __attribute__((ext_vector_type(8))) __bf16 bf16x8;
typedef __attribute__((ext_vector_type(8))) short short8;
typedef __attribute__((ext_vector_type(4))) float floatx4;

__device__ inline float bf2f(short s) {
  union { unsigned u; float f; } c;
  c.u = ((unsigned)(unsigned short)s) << 16;
  return c.f;
}
__device__ inline short f2bf(float f) {
  union { float f; unsigned u; } c; c.f = f;
  unsigned r = 0x7fffu + ((c.u >> 16) & 1u);
  return (short)((c.u + r) >> 16);
}
__device__ inline float silu_f(float v) {
  return v * __builtin_amdgcn_rcpf(1.f + __expf(-v));
}
__device__ inline float softplus_f(float v) {
  return fmaxf(v, 0.f) + log1pf(__expf(-fabsf(v)));
}
// async global->LDS, 16B per lane. LDS dest = wave-uniform base + lane*16.
__device__ inline void gld_lds16(const void* g, void* l) {
  __builtin_amdgcn_global_load_lds(
      (__attribute__((address_space(1))) void*)g,
      (__attribute__((address_space(3))) void*)l, 16, 0, 0);
}

// panel-staged bf16 layout: panel = 16 rows, stored contiguously (K*32 bytes),
// inside: [k-chunk of 8][row-in-panel 16][8 elems].  element (r,k):
__device__ inline size_t permOff(int r, int k, int K) {
  return (((size_t)(r >> 4) * (K >> 3) + (k >> 3)) << 7) + ((r & 15) << 3) + (k & 7);
}

// ---------------- fused pre-pass ---------------------------------------------
// [0,PP0) x->bf16 | weights | [PP4,PP5) bx=b_xp init | [PP5,PP6) d_out init
#define PP0 4096
#define PP1 (PP0 + 4096)
#define PP2 (PP1 + 2048)
#define PP3 (PP2 + 128)
#define PP4 (PP3 + 2048)
#define PP5 (PP4 + 512)
#define PP6 (PP5 + 8192)

__device__ void tile_transpose_perm(const float* __restrict__ in, short* __restrict__ out,
                                    int R, int C, int bx, int by, float (*tile)[33]) {
  const int tx = threadIdx.x & 31, ty = threadIdx.x >> 5;   // 32 x 8
  const int cb = bx * 32, rb = by * 32;
#pragma unroll
  for (int i = 0; i < 32; i += 8) {
    int r = rb + ty + i, c = cb + tx;
    tile[ty + i][tx] = (r < R && c < C) ? in[(size_t)r * C + c] : 0.f;
  }
  __syncthreads();
#pragma unroll
  for (int i = 0; i < 32; i += 8) {
    int orow = cb + ty + i, oc = rb + tx;   // out(row=orow, k=oc) = in[oc][orow]
    if (orow < C && oc < R) out[permOff(orow, oc, R)] = f2bf(tile[tx][ty + i]);
  }
}

__global__ void prepass_kernel(const float* __restrict__ x, short* __restrict__ x_bf,
                               const float* __restrict__ W_in, short* __restrict__ Wt_in,
                               const float* __restrict__ W_dt, const float* __restrict__ W_xp,
                               short* __restrict__ Bcat,
                               const float* __restrict__ W_out, short* __restrict__ Wt_out,
                               const float* __restrict__ b_xp, float* __restrict__ bx,
                               const float* __restrict__ b_out, const float* __restrict__ Dv,
                               float* __restrict__ dout) {
  __shared__ float tile[32][33];
  const int blk = blockIdx.x;
  if (blk < PP0) {
    int o = blk * 256 + threadIdx.x;            // [0, 1M) 16B groups
    int m = o & 15, rest = o >> 4;
    int c = rest & 127, p = rest >> 7;          // K/8 = 128 chunks
    const float* src = x + ((size_t)(p * 16 + m)) * 1024 + c * 8;
    float4 v0 = ((const float4*)src)[0];
    float4 v1 = ((const float4*)src)[1];
    short8 ov;
    ov[0] = f2bf(v0.x); ov[1] = f2bf(v0.y); ov[2] = f2bf(v0.z); ov[3] = f2bf(v0.w);
    ov[4] = f2bf(v1.x); ov[5] = f2bf(v1.y); ov[6] = f2bf(v1.z); ov[7] = f2bf(v1.w);
    ((short8*)x_bf)[o] = ov;
  } else if (blk < PP1) {
    int t = blk - PP0;
    tile_transpose_perm(W_in, Wt_in, 1024, 4096, t & 127, t >> 7, tile);
  } else if (blk < PP2) {
    int t = blk - PP1;
    tile_transpose_perm(W_dt, Bcat, 2048, 1024, t & 31, t >> 5, tile);
  } else if (blk < PP3) {
    int t = blk - PP2;
    tile_transpose_perm(W_xp, Bcat + (size_t)1024 * DINNER, 2048, 64, t & 1, t >> 1, tile);
  } else if (blk < PP4) {
    int t = blk - PP3;
    tile_transpose_perm(W_out, Wt_out, 2048, 1024, t & 31, t >> 5, tile);
  } else if (blk < PP5) {
    // bx init: bx[r][n] = b_xp[n]   (512K floats as float4)
    int idx = (blk - PP4) * 256 + threadIdx.x;   // [0, 131072)
    int n = (idx & 15) * 4;
    float4 bv = { b_xp[n], b_xp[n + 1], b_xp[n + 2], b_xp[n + 3] };
    ((float4*)bx)[idx] = bv;
  } else {
    // d_out init: out = b_out + x*D   (2M float4 groups)
    int idx = (blk - PP5) * 256 + threadIdx.x;   // [0, 2M)
    int c = (idx & 255) * 4;
    float4 xv = ((const float4*)x)[idx];
    float4 ov;
    ov.x = b_out[c + 0] + xv.x * Dv[c + 0];
    ov.y = b_out[c + 1] + xv.y * Dv[c + 1];
    ov.z = b_out[c + 2] + xv.z * Dv[c + 2];
    ov.w = b_out[c + 3] + xv.w * Dv[c + 3];
    ((float4*)dout)[idx] = ov;
  }
}

// ---------------- bf16 GEMM, BK=32 (round-6 structure, best measured) --------
// 1D grid, XCD swizzle: xcd=bid&7 owns bM stripe -> A-stripe stays in one L2.
// MODE 0: full-K; xi=silu (bN<2048) / g=silu (bN>=2048), panel-staged bf16 out
// MODE 1: K-slice z; bN<1024: bf16 dt-partial (stride 1024) at out0+z*M*1024;
//         bN==1024,wc==0: fp32 atomicAdd into bx (out1);  cols>=1088 dropped
// MODE 2: K-slice z; fp32 atomicAdd acc into out0 (stride 1024, pre-inited)
template <int MODE, int KTOT, int KSL, int NB, int Z>
__global__ __launch_bounds__(256) void gemm_bt(
    const short* __restrict__ A, const short* __restrict__ Bt,
    const float* __restrict__ bias,
    void* __restrict__ out0, void* __restrict__ out1)
{
  __shared__ __attribute__((aligned(16))) short sA[128 * 32];
  __shared__ __attribute__((aligned(16))) short sB[128 * 32];

  const int tid = threadIdx.x;
  const int lane = tid & 63;
  const int w = tid >> 6;          // wave 0..3
  const int wr = w >> 1, wc = w & 1;
  const int m = lane & 15, quad = lane >> 4;

  const int xcd = blockIdx.x & 7;
  const int rest = blockIdx.x >> 3;
  constexpr int PXB = 8 * NB;               // blocks per XCD per z-slice
  const int z = rest / PXB;
  const int q2 = rest - z * PXB;
  const int bM = (xcd * 8 + (q2 & 7)) * 128;
  const int bN = (q2 >> 3) * 128;

  floatx4 acc[4][4] = {};

  const size_t PS = (size_t)KTOT * 16;            // panel stride (shorts)
  const short* Apan0 = A  + ((size_t)(bM >> 4) + w) * PS + lane * 8;
  const short* Apan1 = Apan0 + 4 * PS;
  const short* Bpan0 = Bt + ((size_t)(bN >> 4) + w) * PS + lane * 8;
  const short* Bpan1 = Bpan0 + 4 * PS;
  short* dA0 = sA + w * 512;
  short* dA1 = sA + (w + 4) * 512;
  short* dB0 = sB + w * 512;
  short* dB1 = sB + (w + 4) * 512;

  const int kbeg = z * KSL;
#pragma unroll 2
  for (int k0 = kbeg; k0 < kbeg + KSL; k0 += 32) {
    __syncthreads();
    const size_t ko = (size_t)k0 * 16;            // 32 k -> 512 shorts per panel
    gld_lds16(Apan0 + ko, dA0);
    gld_lds16(Apan1 + ko, dA1);
    gld_lds16(Bpan0 + ko, dB0);
    gld_lds16(Bpan1 + ko, dB1);
    __syncthreads();   // drains vmcnt incl. global_load_lds
    bf16x8 af[4], bf[4];
#pragma unroll
    for (int rt = 0; rt < 4; ++rt)
      af[rt] = *(const bf16x8*)(sA + (((wr * 4 + rt) * 64 + quad * 16 + m) << 3));
#pragma unroll
    for (int ct = 0; ct < 4; ++ct)
      bf[ct] = *(const bf16x8*)(sB + (((wc * 4 + ct) * 64 + quad * 16 + m) << 3));
#pragma unroll
    for (int rt = 0; rt < 4; ++rt)
#pragma unroll
      for (int ct = 0; ct < 4; ++ct)
        acc[rt][ct] = __builtin_amdgcn_mfma_f32_16x16x32_bf16(af[rt], bf[ct], acc[rt][ct], 0, 0, 0);
  }

  const int rowbase = bM + wr * 64;
  const int colbase = bN + wc * 64;

  if (MODE == 0) {
    short* dst = (bN < DINNER) ? (short*)out0 : (short*)out1;
    const int cb = (bN < DINNER) ? colbase : colbase - DINNER;
#pragma unroll
    for (int rt = 0; rt < 4; ++rt) {
      const size_t rowPan = ((size_t)((rowbase >> 4) + rt)) << 8;   // *256 chunks
#pragma unroll
      for (int ct = 0; ct < 4; ++ct) {
        const int colA = colbase + ct * 16 + m;      // for bias
        const int colP = cb + ct * 16 + m;           // within 2048-wide target
        const size_t base = ((rowPan + (colP >> 3)) << 7) + (colP & 7) + ((size_t)quad * 32);
#pragma unroll
        for (int reg = 0; reg < 4; ++reg) {
          float val = acc[rt][ct][reg] + bias[colA];
          dst[base + reg * 8] = f2bf(silu_f(val));
        }
      }
    }
  } else if (MODE == 1) {
    if (bN < 1024) {                 // dt columns: bf16 partial, stride 1024
      short* dst = (short*)out0 + (size_t)z * MROWS * 1024;
#pragma unroll
      for (int rt = 0; rt < 4; ++rt)
#pragma unroll
        for (int ct = 0; ct < 4; ++ct) {
          const int col = colbase + ct * 16 + m;
#pragma unroll
          for (int reg = 0; reg < 4; ++reg) {
            const int r = rowbase + rt * 16 + quad * 4 + reg;
            dst[(size_t)r * 1024 + col] = f2bf(acc[rt][ct][reg]);
          }
        }
    } else if (wc == 0) {            // cols 1024..1087 -> bx atomic fp32
      float* bxp = (float*)out1;
#pragma unroll
      for (int rt = 0; rt < 4; ++rt)
#pragma unroll
        for (int ct = 0; ct < 4; ++ct) {
          const int cr = ct * 16 + m;
#pragma unroll
          for (int reg = 0; reg < 4; ++reg) {
            const int r = rowbase + rt * 16 + quad * 4 + reg;
            atomicAdd(&bxp[(size_t)r * DSTATE + cr], acc[rt][ct][reg]);
          }
        }
    }                                // cols >= 1088: pad, drop
  } else {
    float* dst = (float*)out0;       // pre-inited with b_out + x*D
#pragma unroll
    for (int rt = 0; rt < 4; ++rt)
#pragma unroll
      for (int ct = 0; ct < 4; ++ct) {
        const int col = colbase + ct * 16 + m;
#pragma unroll
        for (int reg = 0; reg < 4; ++reg) {
          const int r = rowbase + rt * 16 + quad * 4 + reg;
          atomicAdd(&dst[(size_t)r * 1024 + col], acc[rt][ct][reg]);
        }
      }
  }
}

// ---------------- scan phase1 (fused md/bx combine + chunk scan) -------------
// block (b,c): waves compute md rowsums from dt partials; wave0 runs the scan.
__global__ __launch_bounds__(256) void scan1_fused(
    const short* __restrict__ p2, const float* __restrict__ b_dt,
    const float* __restrict__ A_log, const float* __restrict__ bx,
    float* __restrict__ md_sum, float* __restrict__ chunk_prod,
    float* __restrict__ chunk_end) {
  const int c = blockIdx.x & (NCHUNK - 1);
  const int b = blockIdx.x >> 6;
  const int tid = threadIdx.x, w = tid >> 6, lane = tid & 63;
  __shared__ float mdL[64];
  __shared__ float bxL[64 * 64];

  const int r0 = b * SEQ + c * LCHUNK;
  // stage bx rows into LDS (16KB, coalesced float4)
  const float4* bxg = (const float4*)(bx + (size_t)r0 * DSTATE);
  float4* bxl4 = (float4*)bxL;
  for (int i = tid; i < 1024; i += 256) bxl4[i] = bxg[i];
  // b_dt slice for this lane
  float bd[16];
#pragma unroll
  for (int j = 0; j < 16; ++j) bd[j] = b_dt[lane * 16 + j];
  // md for rows w*16 .. w*16+15
  for (int j = 0; j < 16; ++j) {
    const int i = w * 16 + j;
    const size_t base0 = (size_t)(r0 + i) * 1024 + lane * 16;
    const size_t base1 = base0 + (size_t)MROWS * 1024;
    short8 a0 = *(const short8*)(p2 + base0);
    short8 a1 = *(const short8*)(p2 + base0 + 8);
    short8 c0 = *(const short8*)(p2 + base1);
    short8 c1 = *(const short8*)(p2 + base1 + 8);
    float s = 0.f;
#pragma unroll
    for (int k = 0; k < 8; ++k) {
      s += softplus_f(bf2f(a0[k]) + bf2f(c0[k]) + bd[k]);
      s += softplus_f(bf2f(a1[k]) + bf2f(c1[k]) + bd[8 + k]);
    }
    s += __shfl_xor(s, 1);  s += __shfl_xor(s, 2);  s += __shfl_xor(s, 4);
    s += __shfl_xor(s, 8);  s += __shfl_xor(s, 16); s += __shfl_xor(s, 32);
    if (lane == 0) { mdL[i] = s; md_sum[r0 + i] = s; }
  }
  __syncthreads();
  if (w == 0) {
    const float An = -__expf(A_log[lane]);
    float prod = 1.f, st = 0.f;
    for (int i = 0; i < LCHUNK; ++i) {
      const float a = __expf(An * (mdL[i] * (1.f / DMODEL)));
      st = a * st + bxL[i * 64 + lane];
      prod *= a;
    }
    chunk_prod[(b * NCHUNK + c) * DSTATE + lane] = prod;
    chunk_end [(b * NCHUNK + c) * DSTATE + lane] = st;
  }
}

// phase3: redo own chunk-prefix, recompute a=exp(An*md), emit s_sum
__global__ void scan_phase3(const float* __restrict__ md_sum, const float* __restrict__ A_log,
                            const float* __restrict__ bx,
                            const float* __restrict__ chunk_prod,
                            const float* __restrict__ chunk_end,
                            float* __restrict__ s_sum) {
  const int n = threadIdx.x;
  const int c = blockIdx.x & (NCHUNK - 1);
  const int b = blockIdx.x >> 6;
  const float An = -__expf(A_log[n]);
  float st = 0.f;
  for (int cc = 0; cc < c; ++cc) {
    const size_t idx = ((size_t)(b * NCHUNK + cc)) * DSTATE + n;
    st = chunk_prod[idx] * st + chunk_end[idx];
  }
  const int t0 = c * LCHUNK;
#pragma unroll 4
  for (int i = 0; i < LCHUNK; ++i) {
    const int t = t0 + i;
    const float md = md_sum[b * SEQ + t] * (1.f / DMODEL);
    const float a = __expf(An * md);
    st = a * st + bx[((size_t)(b * SEQ + t)) * DSTATE + n];
    float v = st;
    v += __shfl_xor(v, 32); v += __shfl_xor(v, 16); v += __shfl_xor(v, 8);
    v += __shfl_xor(v, 4);  v += __shfl_xor(v, 2);  v += __shfl_xor(v, 1);
    if (n == 0) s_sum[b * SEQ + t] = v;
  }
}

// ---------------- y = s_sum * xi * g  (panel-staged in AND out, K=2048) ------
__global__ void ymul_kernel(const short* __restrict__ xi, const short* __restrict__ g,
                            const float* __restrict__ s_sum, short* __restrict__ y) {
  const int o = blockIdx.x * 256 + threadIdx.x;    // 16B group index, [0, 2M)
  const int row = ((o >> 12) << 4) | (o & 15);     // panel p = o>>12 (256 chunks)
  const size_t base = (size_t)o * 8;
  const float s = s_sum[row];
  short8 xv = *(const short8*)(xi + base);
  short8 gv = *(const short8*)(g + base);
  short8 yv;
#pragma unroll
  for (int k = 0; k < 8; ++k) yv[k] = f2bf(s * bf2f(xv[k]) * bf2f(gv[k]));
  *(short8*)(y + base) = yv;
}

// ---------------- launch ------------------------------------------------------
extern "C" void kernel_launch(void* const* d_in, const int* in_sizes, int n_in,
                              void* d_out, int out_size, void* d_ws, size_t ws_size,
                              hipStream_t stream) {
  const float* x     = (const float*)d_in[0];
  const float* W_in  = (const float*)d_in[1];
  const float* b_in  = (const float*)d_in[2];
  const float* W_xp  = (const float*)d_in[3];
  const float* b_xp  = (const float*)d_in[4];
  const float* W_dt  = (const float*)d_in[5];
  const float* b_dt  = (const float*)d_in[6];
  const float* W_out = (const float*)d_in[7];
  const float* b_out = (const float*)d_in[8];
  const float* A_log = (const float*)d_in[9];
  const float* Dv    = (const float*)d_in[10];

  char* ws = (char*)d_ws;
  size_t off = 0;
  auto alloc = [&](size_t bytes) -> void* {
    void* p = (void*)(ws + off);
    off += (bytes + 255) & ~(size_t)255;
    return p;
  };
  short* x_bf    = (short*)alloc((size_t)MROWS * DMODEL * 2);
  short* Wt_in   = (short*)alloc((size_t)4096 * 1024 * 2);
  short* Bcat    = (short*)alloc((size_t)1152 * DINNER * 2);
  short* Wt_out  = (short*)alloc((size_t)1024 * 2048 * 2);
  short* xi      = (short*)alloc((size_t)MROWS * DINNER * 2);
  short* gbuf    = (short*)alloc((size_t)MROWS * DINNER * 2);
  short* ybuf    = (short*)alloc((size_t)MROWS * DINNER * 2);
  short* p2      = (short*)alloc((size_t)2 * MROWS * 1024 * 2); // G2 dt partials
  float* md_sum  = (float*)alloc((size_t)MROWS * 4);
  float* bx      = (float*)alloc((size_t)MROWS * DSTATE * 4);
  float* cprod   = (float*)alloc((size_t)2 * NCHUNK * DSTATE * 4);
  float* cend    = (float*)alloc((size_t)2 * NCHUNK * DSTATE * 4);
  float* s_sum   = (float*)alloc((size_t)MROWS * 4);

  // fused pre-pass: x->bf16, weight transposes, bx = b_xp, d_out = b_out + x*D
  prepass_kernel<<<PP6, 256, 0, stream>>>(x, x_bf, W_in, Wt_in, W_dt, W_xp, Bcat,
                                          W_out, Wt_out, b_xp, bx, b_out, Dv,
                                          (float*)d_out);

  // GEMM1: in_proj + silu split (panel-staged out); XCD-swizzled 1D grid
  gemm_bt<0, 1024, 1024, 32, 1><<<2048, 256, 0, stream>>>(x_bf, Wt_in, b_in, xi, gbuf);
  // GEMM2: split-K=2 -> dt bf16 partials + bx fp32 atomics
  gemm_bt<1, 2048, 1024, 9, 2><<<1152, 256, 0, stream>>>(xi, Bcat, nullptr, p2, bx);
  // scan phase1 (fused md/bx combine + chunk scan)
  scan1_fused<<<2 * NCHUNK, 256, 0, stream>>>(p2, b_dt, A_log, bx, md_sum, cprod, cend);
  // scan phase3 (self-computed chunk prefix)
  scan_phase3<<<2 * NCHUNK, DSTATE, 0, stream>>>(md_sum, A_log, bx, cprod, cend, s_sum);
  // y = s_sum * xi * g (panel-staged); xi dead afterwards
  ymul_kernel<<<MROWS * DINNER / 8 / 256, 256, 0, stream>>>(xi, gbuf, s_sum, ybuf);
  // GEMM4: split-K=2, fp32 atomicAdd into pre-inited d_out (no epilogue)
  gemm_bt<2, 2048, 1024, 8, 2><<<1024, 256, 0, stream>>>(ybuf, Wt_out, nullptr, d_out, nullptr);
}